// Round 11
// baseline (703.721 us; speedup 1.0000x reference)
//
#include <hip/hip_runtime.h>
#include <hip/hip_fp16.h>

#define HID 64
#define SH 9          // log2(nodes per bucket)
#define BKN 512       // nodes per bucket
#define MAXB1 256     // max buckets supported (n <= 131072)
#define NBLK 1024     // edge-chunk blocks for the counting sort
typedef unsigned int u32;

// ---------------------------------------------------------------- per-(block,bucket) histogram
// deterministic contiguous chunks; LDS-staged; NO global atomics
__global__ __launch_bounds__(256) void count_chunks(const int* __restrict__ dst,
                                                    int* __restrict__ cnt2,
                                                    int E, int nbk) {
  __shared__ int lc[MAXB1];
  const int t = threadIdx.x;
  for (int b = t; b < nbk; b += 256) lc[b] = 0;
  __syncthreads();
  const int C = (E + NBLK - 1) / NBLK;
  const int s0 = blockIdx.x * C;
  const int s1 = min(s0 + C, E);
  for (int i = s0 + t; i < s1; i += 256) atomicAdd(&lc[dst[i] >> SH], 1);
  __syncthreads();
  for (int b = t; b < nbk; b += 256)
    cnt2[(size_t)b * NBLK + blockIdx.x] = lc[b];  // bucket-major for seq scan
}

// ---------------------------------------------------------------- scan the 196*1024 counts
// order m = b*NBLK + blk -> bucket b's block-segments are contiguous & dense.
__global__ __launch_bounds__(256) void scan_chunks(const int* __restrict__ cnt2,
                                                   int* __restrict__ off,
                                                   int* __restrict__ boff,
                                                   int nbk, int E) {
  __shared__ int s[256];
  const int t = threadIdx.x;
  const int total = nbk * NBLK;
  const int CH = (total + 255) / 256;
  int sum = 0;
  for (int k = 0; k < CH; ++k) {
    const int m = t * CH + k;
    if (m < total) sum += cnt2[m];
  }
  s[t] = sum;
  __syncthreads();
  for (int o = 1; o < 256; o <<= 1) {
    const int u = (t >= o) ? s[t - o] : 0;
    __syncthreads();
    s[t] += u;
    __syncthreads();
  }
  int run = s[t] - sum;  // exclusive prefix of this thread's chunk
  for (int k = 0; k < CH; ++k) {
    const int m = t * CH + k;
    if (m < total) {
      off[m] = run;
      if ((m & (NBLK - 1)) == 0) boff[m / NBLK] = run;  // bucket base
      run += cnt2[m];
    }
  }
  if (t == 255) boff[nbk] = E;
}

// ---------------------------------------------------------------- fill pairs, deterministic
// packed u32: (dstLocal<<17) | src. Each (block,bucket) segment is block-private
// and contiguous; boundary 64B lines shared by at most 2 adjacent blocks.
__global__ __launch_bounds__(256) void fill_pairs(const int* __restrict__ src,
                                                  const int* __restrict__ dst,
                                                  const int* __restrict__ off,
                                                  u32* __restrict__ pairs,
                                                  int E, int nbk) {
  __shared__ int lbase[MAXB1];
  __shared__ int lrank[MAXB1];
  const int t = threadIdx.x;
  for (int b = t; b < nbk; b += 256) {
    lbase[b] = off[(size_t)b * NBLK + blockIdx.x];
    lrank[b] = 0;
  }
  __syncthreads();
  const int C = (E + NBLK - 1) / NBLK;
  const int s0 = blockIdx.x * C;
  const int s1 = min(s0 + C, E);
  for (int i = s0 + t; i < s1; i += 256) {
    const int d = dst[i];
    const int b = d >> SH;
    const int r = atomicAdd(&lrank[b], 1);
    pairs[lbase[b] + r] = ((u32)(d & (BKN - 1)) << 17) | (u32)src[i];
  }
}

// ---------------------------------------------------------------- per-node degree + dinv
__global__ __launch_bounds__(256) void bucket_deg(const u32* __restrict__ pairs,
                                                  const int* __restrict__ boff,
                                                  int* __restrict__ deg,
                                                  float* __restrict__ dinv, int n) {
  __shared__ int ldeg[BKN];
  const int bkt = blockIdx.x;
  const int t = threadIdx.x;
  for (int i = t; i < BKN; i += 256) ldeg[i] = 0;
  __syncthreads();
  const int beg = boff[bkt], end = boff[bkt + 1];
  for (int e = beg + t; e < end; e += 256) atomicAdd(&ldeg[pairs[e] >> 17], 1);
  __syncthreads();
  const int base = bkt * BKN;
  for (int i = t; i < BKN; i += 256) {
    const int node = base + i;
    if (node < n) {
      const int dg = ldeg[i];
      deg[node] = dg;
      dinv[node] = rsqrtf((float)(dg + 1));  // +1 self-loop
    }
  }
}

// ---------------------------------------------------------------- scan (rowptr)
__global__ __launch_bounds__(256) void scan_blocks(const int* __restrict__ deg,
                                                   int* __restrict__ rowptr,
                                                   int* __restrict__ bsum, int n) {
  __shared__ int s[256];
  const int t = threadIdx.x;
  const int i = blockIdx.x * 256 + t;
  const int v = (i < n) ? deg[i] : 0;
  s[t] = v;
  __syncthreads();
  for (int off = 1; off < 256; off <<= 1) {
    const int u = (t >= off) ? s[t - off] : 0;
    __syncthreads();
    s[t] += u;
    __syncthreads();
  }
  if (i < n) rowptr[i] = s[t] - v;
  if (t == 255) bsum[blockIdx.x] = s[255];
}

__global__ __launch_bounds__(512) void scan_top(int* bsum, int nb) {
  __shared__ int s[512];
  const int t = threadIdx.x;
  const int v = (t < nb) ? bsum[t] : 0;
  s[t] = v;
  __syncthreads();
  for (int off = 1; off < 512; off <<= 1) {
    const int u = (t >= off) ? s[t - off] : 0;
    __syncthreads();
    s[t] += u;
    __syncthreads();
  }
  if (t < nb) bsum[t] = s[t] - v;
}

__global__ __launch_bounds__(256) void add_offsets(int* __restrict__ rowptr,
                                                   const int* __restrict__ bsum,
                                                   int n, int E) {
  const int i = blockIdx.x * 256 + threadIdx.x;
  if (i < n) rowptr[i] += bsum[blockIdx.x];
  if (i == 0) rowptr[n] = E;
}

// ---------------------------------------------------------------- exact CSR fill
__global__ __launch_bounds__(256) void local_fill2(const u32* __restrict__ pairs,
                                                   const int* __restrict__ boff,
                                                   const int* __restrict__ rowptr,
                                                   int* __restrict__ colidx, int n) {
  __shared__ int lcur[BKN / 2];
  const int bkt = blockIdx.x >> 1;
  const int half = blockIdx.x & 1;
  const int nb0 = bkt * BKN + half * (BKN / 2);
  const int t = threadIdx.x;
  if (t < BKN / 2) {
    const int node = nb0 + t;
    lcur[t] = (node < n) ? rowptr[node] : 0;
  }
  __syncthreads();
  const int beg = boff[bkt], end = boff[bkt + 1];
  for (int e = beg + t; e < end; e += 256) {
    const u32 p = pairs[e];
    const int dloc = (int)(p >> 17);
    if ((dloc >> 8) == half) {
      const int pos = atomicAdd(&lcur[dloc & 255], 1);
      colidx[pos] = (int)(p & 0x1FFFF);
    }
  }
}

// ---------------------------------------------------------------- dense transform
// g[i, c] = fp16( dinv[i] * sum_k x[i,k] * W[k,c] )   (row-major again)
template <int K>
__global__ __launch_bounds__(256) void gemm_nodes(const float* __restrict__ x,
                                                  const float* __restrict__ W,
                                                  const float* __restrict__ dinv,
                                                  __half* __restrict__ out) {
  __shared__ float Wl[K * 64];
  __shared__ float xl[16][K];
  const int tid = threadIdx.x;
  for (int i = tid; i < K * 16; i += 256)
    reinterpret_cast<float4*>(Wl)[i] = reinterpret_cast<const float4*>(W)[i];
  const int row0 = blockIdx.x * 16;
  for (int i = tid; i < 16 * (K / 4); i += 256) {
    const int r = i / (K / 4), q = i % (K / 4);
    reinterpret_cast<float4*>(&xl[r][0])[q] =
        reinterpret_cast<const float4*>(x + (size_t)(row0 + r) * K)[q];
  }
  __syncthreads();
  const int c = tid & 63;
  const int rbase = tid >> 6;
  for (int rr = rbase; rr < 16; rr += 4) {
    float acc = 0.f;
#pragma unroll
    for (int k = 0; k < K; k += 4) {
      const float4 xv = *reinterpret_cast<const float4*>(&xl[rr][k]);
      acc = fmaf(xv.x, Wl[(k + 0) * 64 + c], acc);
      acc = fmaf(xv.y, Wl[(k + 1) * 64 + c], acc);
      acc = fmaf(xv.z, Wl[(k + 2) * 64 + c], acc);
      acc = fmaf(xv.w, Wl[(k + 3) * 64 + c], acc);
    }
    const int grow = row0 + rr;
    out[(size_t)grow * 64 + c] = __float2half(acc * dinv[grow]);
  }
}

// ---------------------------------------------------------------- pull aggregation
// one wave per node, 2 edges per load instr (half2 rows), 8 loads in flight
// per half-wave = 16 edges per wave-iter.
__global__ __launch_bounds__(256) void gather_agg(const int* __restrict__ rowptr,
                                                  const int* __restrict__ colidx,
                                                  const __half2* __restrict__ g2,
                                                  const float* __restrict__ dinv,
                                                  const float* __restrict__ bias,
                                                  float* __restrict__ out, int n) {
  const int lane = threadIdx.x & 63;
  const int node = (blockIdx.x * 256 + threadIdx.x) >> 6;
  if (node >= n) return;
  const int h = lane >> 5;   // which edge of each pair this half-wave owns
  const int l = lane & 31;   // feature-pair index
  const int beg = rowptr[node];
  const int end = rowptr[node + 1];
  float2 acc = {0.f, 0.f};
  int e = beg + h;
  for (; e + 14 < end; e += 16) {  // 16 edges/wave-iter, 8 loads in flight/half
    const int s0 = colidx[e + 0],  s1 = colidx[e + 2];
    const int s2 = colidx[e + 4],  s3 = colidx[e + 6];
    const int s4 = colidx[e + 8],  s5 = colidx[e + 10];
    const int s6 = colidx[e + 12], s7 = colidx[e + 14];
    const float2 v0 = __half22float2(g2[(size_t)s0 * 32 + l]);
    const float2 v1 = __half22float2(g2[(size_t)s1 * 32 + l]);
    const float2 v2 = __half22float2(g2[(size_t)s2 * 32 + l]);
    const float2 v3 = __half22float2(g2[(size_t)s3 * 32 + l]);
    const float2 v4 = __half22float2(g2[(size_t)s4 * 32 + l]);
    const float2 v5 = __half22float2(g2[(size_t)s5 * 32 + l]);
    const float2 v6 = __half22float2(g2[(size_t)s6 * 32 + l]);
    const float2 v7 = __half22float2(g2[(size_t)s7 * 32 + l]);
    acc.x += ((v0.x + v1.x) + (v2.x + v3.x)) + ((v4.x + v5.x) + (v6.x + v7.x));
    acc.y += ((v0.y + v1.y) + (v2.y + v3.y)) + ((v4.y + v5.y) + (v6.y + v7.y));
  }
  for (; e + 6 < end; e += 8) {  // 8 edges/wave-iter
    const int s0 = colidx[e + 0], s1 = colidx[e + 2];
    const int s2 = colidx[e + 4], s3 = colidx[e + 6];
    const float2 v0 = __half22float2(g2[(size_t)s0 * 32 + l]);
    const float2 v1 = __half22float2(g2[(size_t)s1 * 32 + l]);
    const float2 v2 = __half22float2(g2[(size_t)s2 * 32 + l]);
    const float2 v3 = __half22float2(g2[(size_t)s3 * 32 + l]);
    acc.x += (v0.x + v1.x) + (v2.x + v3.x);
    acc.y += (v0.y + v1.y) + (v2.y + v3.y);
  }
  for (; e < end; e += 2) {  // ragged tail
    const float2 v = __half22float2(g2[(size_t)colidx[e] * 32 + l]);
    acc.x += v.x;
    acc.y += v.y;
  }
  // cross-half combine
  acc.x += __shfl_xor(acc.x, 32);
  acc.y += __shfl_xor(acc.y, 32);
  // self-loop
  const float2 sv = __half22float2(g2[(size_t)node * 32 + l]);
  acc.x += sv.x;
  acc.y += sv.y;
  const float di = dinv[node];
  const float2 bb = reinterpret_cast<const float2*>(bias)[l];
  float2 r;
  r.x = fmaxf(fmaf(acc.x, di, bb.x), 0.f);
  r.y = fmaxf(fmaf(acc.y, di, bb.y), 0.f);
  if (h == 0) reinterpret_cast<float2*>(out)[(size_t)node * 32 + l] = r;
}

// ---------------------------------------------------------------- final FC (64 -> 11)
__global__ __launch_bounds__(256) void gemm_fc(const float* __restrict__ h,
                                               const float* __restrict__ W,
                                               const float* __restrict__ b,
                                               float* __restrict__ out) {
  __shared__ float Wl[772];
  __shared__ float xl[16][68];
  const int tid = threadIdx.x;
  for (int i = tid; i < 772; i += 256) Wl[i] = 0.f;
  __syncthreads();
  for (int i = tid; i < 64 * 11; i += 256) Wl[(i / 11) * 12 + (i % 11)] = W[i];
  const int row0 = blockIdx.x * 16;
  for (int i = tid; i < 16 * 16; i += 256) {
    const int r = i >> 4, q = i & 15;
    const float4 v = reinterpret_cast<const float4*>(h + (size_t)(row0 + r) * 64)[q];
    xl[r][q * 4 + 0] = v.x; xl[r][q * 4 + 1] = v.y;
    xl[r][q * 4 + 2] = v.z; xl[r][q * 4 + 3] = v.w;
  }
  __syncthreads();
  const int r = tid >> 4, c = tid & 15;
  float acc = 0.f;
#pragma unroll
  for (int k = 0; k < 64; k += 4) {
    acc = fmaf(xl[r][k + 0], Wl[(k + 0) * 12 + c], acc);
    acc = fmaf(xl[r][k + 1], Wl[(k + 1) * 12 + c], acc);
    acc = fmaf(xl[r][k + 2], Wl[(k + 2) * 12 + c], acc);
    acc = fmaf(xl[r][k + 3], Wl[(k + 3) * 12 + c], acc);
  }
  if (c < 11) out[(size_t)(row0 + r) * 11 + c] = acc + b[c];
}

// ---------------------------------------------------------------- launch
extern "C" void kernel_launch(void* const* d_in, const int* in_sizes, int n_in,
                              void* d_out, int out_size, void* d_ws, size_t ws_size,
                              hipStream_t stream) {
  const float* x   = (const float*)d_in[0];
  const int*   ei  = (const int*)d_in[1];   // [2, E] int32
  const float* W1  = (const float*)d_in[2];
  const float* b1  = (const float*)d_in[3];
  const float* W2  = (const float*)d_in[4];
  const float* b2  = (const float*)d_in[5];
  const float* Wfc = (const float*)d_in[6];
  const float* bfc = (const float*)d_in[7];
  float* out = (float*)d_out;

  const int n = in_sizes[0] / 128;  // 100000
  const int E = in_sizes[1] / 2;    // 3200000
  const int* src = ei;
  const int* dst = ei + E;
  const int nbk = (n + BKN - 1) >> SH;  // 196 buckets

  char* ws = (char*)d_ws;
  size_t o = 0;
  auto alloc = [&](size_t bytes) {
    char* p = ws + o;
    o += (bytes + 255) & ~(size_t)255;
    return p;
  };
  int*    deg    = (int*)   alloc((size_t)n * 4);
  float*  dinv   = (float*) alloc((size_t)n * 4);
  int*    rowptr = (int*)   alloc((size_t)(n + 1) * 4);
  int*    bsum   = (int*)   alloc(512 * 4);
  int*    cnt2   = (int*)   alloc((size_t)nbk * NBLK * 4);        // [b][blk]
  int*    off    = (int*)   alloc((size_t)nbk * NBLK * 4);        // [b][blk]
  int*    boff   = (int*)   alloc((size_t)(nbk + 1) * 4);
  u32*    pairs  = (u32*)   alloc((size_t)E * 4);
  int*    colidx = (int*)   alloc((size_t)E * 4);
  __half* B0h    = (__half*)alloc((size_t)n * HID * 2);           // g fp16
  float*  B1     = (float*) alloc((size_t)n * HID * 4);           // layer out
  if (o > ws_size) return;

  const int nb = (n + 255) / 256;  // 391 scan blocks
  const int gblocks = n / 16;      // 6250 gemm blocks

  // ---- graph preprocessing (deterministic counting sort; no global atomics)
  count_chunks<<<NBLK, 256, 0, stream>>>(dst, cnt2, E, nbk);
  scan_chunks<<<1, 256, 0, stream>>>(cnt2, off, boff, nbk, E);
  fill_pairs<<<NBLK, 256, 0, stream>>>(src, dst, off, pairs, E, nbk);
  bucket_deg<<<nbk, 256, 0, stream>>>(pairs, boff, deg, dinv, n);
  scan_blocks<<<nb, 256, 0, stream>>>(deg, rowptr, bsum, n);
  scan_top<<<1, 512, 0, stream>>>(bsum, nb);
  add_offsets<<<nb, 256, 0, stream>>>(rowptr, bsum, n, E);
  local_fill2<<<nbk * 2, 256, 0, stream>>>(pairs, boff, rowptr, colidx, n);

  const int pull_blocks = (n * 64 + 255) / 256;  // one wave per node

  // ---- layer 1
  gemm_nodes<128><<<gblocks, 256, 0, stream>>>(x, W1, dinv, B0h);
  gather_agg<<<pull_blocks, 256, 0, stream>>>(rowptr, colidx,
      (const __half2*)B0h, dinv, b1, B1, n);

  // ---- layer 2
  gemm_nodes<64><<<gblocks, 256, 0, stream>>>(B1, W2, dinv, B0h);
  gather_agg<<<pull_blocks, 256, 0, stream>>>(rowptr, colidx,
      (const __half2*)B0h, dinv, b2, B1, n);

  // ---- FC head
  gemm_fc<<<gblocks, 256, 0, stream>>>(B1, Wfc, bfc, out);
}

// Round 12
// 326.950 us; speedup vs baseline: 2.1524x; 2.1524x over previous
//
#include <hip/hip_runtime.h>
#include <hip/hip_fp16.h>

#define HID 64
#define SH 9          // log2(nodes per bucket)
#define BKN 512       // nodes per bucket
#define MAXB1 256     // max buckets supported (n <= 131072)
#define NBLK 512      // edge-chunk blocks for the counting sort
typedef unsigned int u32;

// ---------------------------------------------------------------- per-(block,bucket) histogram
// deterministic contiguous chunks; LDS-staged; NO global atomics
__global__ __launch_bounds__(256) void count_chunks(const int* __restrict__ dst,
                                                    int* __restrict__ cnt2,
                                                    int E, int nbk) {
  __shared__ int lc[MAXB1];
  const int t = threadIdx.x;
  for (int b = t; b < nbk; b += 256) lc[b] = 0;
  __syncthreads();
  const int C = (E + NBLK - 1) / NBLK;
  const int s0 = blockIdx.x * C;
  const int s1 = min(s0 + C, E);
  for (int i = s0 + t; i < s1; i += 256) atomicAdd(&lc[dst[i] >> SH], 1);
  __syncthreads();
  for (int b = t; b < nbk; b += 256)
    cnt2[(size_t)b * NBLK + blockIdx.x] = lc[b];  // bucket-major for the scan
}

// ---------------------------------------------------------------- generic hierarchical scan
__global__ __launch_bounds__(256) void scan_blocks(const int* __restrict__ v_in,
                                                   int* __restrict__ excl,
                                                   int* __restrict__ bsum, int n) {
  __shared__ int s[256];
  const int t = threadIdx.x;
  const int i = blockIdx.x * 256 + t;
  const int v = (i < n) ? v_in[i] : 0;
  s[t] = v;
  __syncthreads();
  for (int off = 1; off < 256; off <<= 1) {
    const int u = (t >= off) ? s[t - off] : 0;
    __syncthreads();
    s[t] += u;
    __syncthreads();
  }
  if (i < n) excl[i] = s[t] - v;
  if (t == 255) bsum[blockIdx.x] = s[255];
}

__global__ __launch_bounds__(512) void scan_top(int* bsum, int nb) {
  __shared__ int s[512];
  const int t = threadIdx.x;
  const int v = (t < nb) ? bsum[t] : 0;
  s[t] = v;
  __syncthreads();
  for (int off = 1; off < 512; off <<= 1) {
    const int u = (t >= off) ? s[t - off] : 0;
    __syncthreads();
    s[t] += u;
    __syncthreads();
  }
  if (t < nb) bsum[t] = s[t] - v;
}

// add block offsets to the cnt2-scan and extract per-bucket bases
__global__ __launch_bounds__(256) void add_offsets2(int* __restrict__ off,
                                                    const int* __restrict__ bsum,
                                                    int* __restrict__ boff,
                                                    int NE, int E, int nbk) {
  const int m = blockIdx.x * 256 + threadIdx.x;
  if (m < NE) {
    const int v = off[m] + bsum[blockIdx.x];
    off[m] = v;
    if ((m & (NBLK - 1)) == 0) boff[m >> 9] = v;  // NBLK = 512
  }
  if (m == 0) boff[nbk] = E;
}

// plain add_offsets for the rowptr scan
__global__ __launch_bounds__(256) void add_offsets(int* __restrict__ rowptr,
                                                   const int* __restrict__ bsum,
                                                   int n, int E) {
  const int i = blockIdx.x * 256 + threadIdx.x;
  if (i < n) rowptr[i] += bsum[blockIdx.x];
  if (i == 0) rowptr[n] = E;
}

// ---------------------------------------------------------------- fill pairs, deterministic
// packed u32: (dstLocal<<17) | src. Each (block,bucket) segment is block-private
// and contiguous; boundary 64B lines shared by at most 2 adjacent blocks.
__global__ __launch_bounds__(256) void fill_pairs(const int* __restrict__ src,
                                                  const int* __restrict__ dst,
                                                  const int* __restrict__ off,
                                                  u32* __restrict__ pairs,
                                                  int E, int nbk) {
  __shared__ int lbase[MAXB1];
  __shared__ int lrank[MAXB1];
  const int t = threadIdx.x;
  for (int b = t; b < nbk; b += 256) {
    lbase[b] = off[(size_t)b * NBLK + blockIdx.x];
    lrank[b] = 0;
  }
  __syncthreads();
  const int C = (E + NBLK - 1) / NBLK;
  const int s0 = blockIdx.x * C;
  const int s1 = min(s0 + C, E);
  for (int i = s0 + t; i < s1; i += 256) {
    const int d = dst[i];
    const int b = d >> SH;
    const int r = atomicAdd(&lrank[b], 1);
    pairs[lbase[b] + r] = ((u32)(d & (BKN - 1)) << 17) | (u32)src[i];
  }
}

// ---------------------------------------------------------------- per-node degree + dinv
__global__ __launch_bounds__(256) void bucket_deg(const u32* __restrict__ pairs,
                                                  const int* __restrict__ boff,
                                                  int* __restrict__ deg,
                                                  float* __restrict__ dinv, int n) {
  __shared__ int ldeg[BKN];
  const int bkt = blockIdx.x;
  const int t = threadIdx.x;
  for (int i = t; i < BKN; i += 256) ldeg[i] = 0;
  __syncthreads();
  const int beg = boff[bkt], end = boff[bkt + 1];
  for (int e = beg + t; e < end; e += 256) atomicAdd(&ldeg[pairs[e] >> 17], 1);
  __syncthreads();
  const int base = bkt * BKN;
  for (int i = t; i < BKN; i += 256) {
    const int node = base + i;
    if (node < n) {
      const int dg = ldeg[i];
      deg[node] = dg;
      dinv[node] = rsqrtf((float)(dg + 1));  // +1 self-loop
    }
  }
}

// ---------------------------------------------------------------- exact CSR fill
__global__ __launch_bounds__(256) void local_fill2(const u32* __restrict__ pairs,
                                                   const int* __restrict__ boff,
                                                   const int* __restrict__ rowptr,
                                                   int* __restrict__ colidx, int n) {
  __shared__ int lcur[BKN / 2];
  const int bkt = blockIdx.x >> 1;
  const int half = blockIdx.x & 1;
  const int nb0 = bkt * BKN + half * (BKN / 2);
  const int t = threadIdx.x;
  if (t < BKN / 2) {
    const int node = nb0 + t;
    lcur[t] = (node < n) ? rowptr[node] : 0;
  }
  __syncthreads();
  const int beg = boff[bkt], end = boff[bkt + 1];
  for (int e = beg + t; e < end; e += 256) {
    const u32 p = pairs[e];
    const int dloc = (int)(p >> 17);
    if ((dloc >> 8) == half) {
      const int pos = atomicAdd(&lcur[dloc & 255], 1);
      colidx[pos] = (int)(p & 0x1FFFF);
    }
  }
}

// ---------------------------------------------------------------- dense transform
// g[i, c] = fp16( dinv[i] * sum_k x[i,k] * W[k,c] )
template <int K>
__global__ __launch_bounds__(256) void gemm_nodes(const float* __restrict__ x,
                                                  const float* __restrict__ W,
                                                  const float* __restrict__ dinv,
                                                  __half* __restrict__ out) {
  __shared__ float Wl[K * 64];
  __shared__ float xl[16][K];
  const int tid = threadIdx.x;
  for (int i = tid; i < K * 16; i += 256)
    reinterpret_cast<float4*>(Wl)[i] = reinterpret_cast<const float4*>(W)[i];
  const int row0 = blockIdx.x * 16;
  for (int i = tid; i < 16 * (K / 4); i += 256) {
    const int r = i / (K / 4), q = i % (K / 4);
    reinterpret_cast<float4*>(&xl[r][0])[q] =
        reinterpret_cast<const float4*>(x + (size_t)(row0 + r) * K)[q];
  }
  __syncthreads();
  const int c = tid & 63;
  const int rbase = tid >> 6;
  for (int rr = rbase; rr < 16; rr += 4) {
    float acc = 0.f;
#pragma unroll
    for (int k = 0; k < K; k += 4) {
      const float4 xv = *reinterpret_cast<const float4*>(&xl[rr][k]);
      acc = fmaf(xv.x, Wl[(k + 0) * 64 + c], acc);
      acc = fmaf(xv.y, Wl[(k + 1) * 64 + c], acc);
      acc = fmaf(xv.z, Wl[(k + 2) * 64 + c], acc);
      acc = fmaf(xv.w, Wl[(k + 3) * 64 + c], acc);
    }
    const int grow = row0 + rr;
    out[(size_t)grow * 64 + c] = __float2half(acc * dinv[grow]);
  }
}

// ---------------------------------------------------------------- pull aggregation
// one wave per node, 2 edges per load instr (half2 rows), 8 loads in flight
// per half-wave = 16 edges per wave-iter.
__global__ __launch_bounds__(256) void gather_agg(const int* __restrict__ rowptr,
                                                  const int* __restrict__ colidx,
                                                  const __half2* __restrict__ g2,
                                                  const float* __restrict__ dinv,
                                                  const float* __restrict__ bias,
                                                  float* __restrict__ out, int n) {
  const int lane = threadIdx.x & 63;
  const int node = (blockIdx.x * 256 + threadIdx.x) >> 6;
  if (node >= n) return;
  const int h = lane >> 5;   // which edge of each pair this half-wave owns
  const int l = lane & 31;   // feature-pair index
  const int beg = rowptr[node];
  const int end = rowptr[node + 1];
  float2 acc = {0.f, 0.f};
  int e = beg + h;
  for (; e + 14 < end; e += 16) {  // 16 edges/wave-iter, 8 loads in flight/half
    const int s0 = colidx[e + 0],  s1 = colidx[e + 2];
    const int s2 = colidx[e + 4],  s3 = colidx[e + 6];
    const int s4 = colidx[e + 8],  s5 = colidx[e + 10];
    const int s6 = colidx[e + 12], s7 = colidx[e + 14];
    const float2 v0 = __half22float2(g2[(size_t)s0 * 32 + l]);
    const float2 v1 = __half22float2(g2[(size_t)s1 * 32 + l]);
    const float2 v2 = __half22float2(g2[(size_t)s2 * 32 + l]);
    const float2 v3 = __half22float2(g2[(size_t)s3 * 32 + l]);
    const float2 v4 = __half22float2(g2[(size_t)s4 * 32 + l]);
    const float2 v5 = __half22float2(g2[(size_t)s5 * 32 + l]);
    const float2 v6 = __half22float2(g2[(size_t)s6 * 32 + l]);
    const float2 v7 = __half22float2(g2[(size_t)s7 * 32 + l]);
    acc.x += ((v0.x + v1.x) + (v2.x + v3.x)) + ((v4.x + v5.x) + (v6.x + v7.x));
    acc.y += ((v0.y + v1.y) + (v2.y + v3.y)) + ((v4.y + v5.y) + (v6.y + v7.y));
  }
  for (; e + 6 < end; e += 8) {  // 8 edges/wave-iter
    const int s0 = colidx[e + 0], s1 = colidx[e + 2];
    const int s2 = colidx[e + 4], s3 = colidx[e + 6];
    const float2 v0 = __half22float2(g2[(size_t)s0 * 32 + l]);
    const float2 v1 = __half22float2(g2[(size_t)s1 * 32 + l]);
    const float2 v2 = __half22float2(g2[(size_t)s2 * 32 + l]);
    const float2 v3 = __half22float2(g2[(size_t)s3 * 32 + l]);
    acc.x += (v0.x + v1.x) + (v2.x + v3.x);
    acc.y += (v0.y + v1.y) + (v2.y + v3.y);
  }
  for (; e < end; e += 2) {  // ragged tail
    const float2 v = __half22float2(g2[(size_t)colidx[e] * 32 + l]);
    acc.x += v.x;
    acc.y += v.y;
  }
  // cross-half combine
  acc.x += __shfl_xor(acc.x, 32);
  acc.y += __shfl_xor(acc.y, 32);
  // self-loop
  const float2 sv = __half22float2(g2[(size_t)node * 32 + l]);
  acc.x += sv.x;
  acc.y += sv.y;
  const float di = dinv[node];
  const float2 bb = reinterpret_cast<const float2*>(bias)[l];
  float2 r;
  r.x = fmaxf(fmaf(acc.x, di, bb.x), 0.f);
  r.y = fmaxf(fmaf(acc.y, di, bb.y), 0.f);
  if (h == 0) reinterpret_cast<float2*>(out)[(size_t)node * 32 + l] = r;
}

// ---------------------------------------------------------------- final FC (64 -> 11)
__global__ __launch_bounds__(256) void gemm_fc(const float* __restrict__ h,
                                               const float* __restrict__ W,
                                               const float* __restrict__ b,
                                               float* __restrict__ out) {
  __shared__ float Wl[772];
  __shared__ float xl[16][68];
  const int tid = threadIdx.x;
  for (int i = tid; i < 772; i += 256) Wl[i] = 0.f;
  __syncthreads();
  for (int i = tid; i < 64 * 11; i += 256) Wl[(i / 11) * 12 + (i % 11)] = W[i];
  const int row0 = blockIdx.x * 16;
  for (int i = tid; i < 16 * 16; i += 256) {
    const int r = i >> 4, q = i & 15;
    const float4 v = reinterpret_cast<const float4*>(h + (size_t)(row0 + r) * 64)[q];
    xl[r][q * 4 + 0] = v.x; xl[r][q * 4 + 1] = v.y;
    xl[r][q * 4 + 2] = v.z; xl[r][q * 4 + 3] = v.w;
  }
  __syncthreads();
  const int r = tid >> 4, c = tid & 15;
  float acc = 0.f;
#pragma unroll
  for (int k = 0; k < 64; k += 4) {
    acc = fmaf(xl[r][k + 0], Wl[(k + 0) * 12 + c], acc);
    acc = fmaf(xl[r][k + 1], Wl[(k + 1) * 12 + c], acc);
    acc = fmaf(xl[r][k + 2], Wl[(k + 2) * 12 + c], acc);
    acc = fmaf(xl[r][k + 3], Wl[(k + 3) * 12 + c], acc);
  }
  if (c < 11) out[(size_t)(row0 + r) * 11 + c] = acc + b[c];
}

// ---------------------------------------------------------------- launch
extern "C" void kernel_launch(void* const* d_in, const int* in_sizes, int n_in,
                              void* d_out, int out_size, void* d_ws, size_t ws_size,
                              hipStream_t stream) {
  const float* x   = (const float*)d_in[0];
  const int*   ei  = (const int*)d_in[1];   // [2, E] int32
  const float* W1  = (const float*)d_in[2];
  const float* b1  = (const float*)d_in[3];
  const float* W2  = (const float*)d_in[4];
  const float* b2  = (const float*)d_in[5];
  const float* Wfc = (const float*)d_in[6];
  const float* bfc = (const float*)d_in[7];
  float* out = (float*)d_out;

  const int n = in_sizes[0] / 128;  // 100000
  const int E = in_sizes[1] / 2;    // 3200000
  const int* src = ei;
  const int* dst = ei + E;
  const int nbk = (n + BKN - 1) >> SH;  // 196 buckets
  const int NE = nbk * NBLK;            // 100352 count entries

  char* ws = (char*)d_ws;
  size_t o = 0;
  auto alloc = [&](size_t bytes) {
    char* p = ws + o;
    o += (bytes + 255) & ~(size_t)255;
    return p;
  };
  int*    deg    = (int*)   alloc((size_t)n * 4);
  float*  dinv   = (float*) alloc((size_t)n * 4);
  int*    rowptr = (int*)   alloc((size_t)(n + 1) * 4);
  int*    bsum   = (int*)   alloc(512 * 4);
  int*    cnt2   = (int*)   alloc((size_t)NE * 4);      // [b][blk]
  int*    off    = (int*)   alloc((size_t)NE * 4);      // scanned
  int*    bsum2  = (int*)   alloc(512 * 4);
  int*    boff   = (int*)   alloc((size_t)(nbk + 1) * 4);
  u32*    pairs  = (u32*)   alloc((size_t)E * 4);
  int*    colidx = (int*)   alloc((size_t)E * 4);
  __half* B0h    = (__half*)alloc((size_t)n * HID * 2); // g fp16
  float*  B1     = (float*) alloc((size_t)n * HID * 4); // layer out
  if (o > ws_size) return;

  const int nb  = (n + 255) / 256;   // 391 rowptr-scan blocks
  const int nb2 = (NE + 255) / 256;  // 392 offset-scan blocks
  const int gblocks = n / 16;        // 6250 gemm blocks

  // ---- graph preprocessing (deterministic counting sort; no global atomics)
  count_chunks<<<NBLK, 256, 0, stream>>>(dst, cnt2, E, nbk);
  scan_blocks<<<nb2, 256, 0, stream>>>(cnt2, off, bsum2, NE);
  scan_top<<<1, 512, 0, stream>>>(bsum2, nb2);
  add_offsets2<<<nb2, 256, 0, stream>>>(off, bsum2, boff, NE, E, nbk);
  fill_pairs<<<NBLK, 256, 0, stream>>>(src, dst, off, pairs, E, nbk);
  bucket_deg<<<nbk, 256, 0, stream>>>(pairs, boff, deg, dinv, n);
  scan_blocks<<<nb, 256, 0, stream>>>(deg, rowptr, bsum, n);
  scan_top<<<1, 512, 0, stream>>>(bsum, nb);
  add_offsets<<<nb, 256, 0, stream>>>(rowptr, bsum, n, E);
  local_fill2<<<nbk * 2, 256, 0, stream>>>(pairs, boff, rowptr, colidx, n);

  const int pull_blocks = (n * 64 + 255) / 256;  // one wave per node

  // ---- layer 1
  gemm_nodes<128><<<gblocks, 256, 0, stream>>>(x, W1, dinv, B0h);
  gather_agg<<<pull_blocks, 256, 0, stream>>>(rowptr, colidx,
      (const __half2*)B0h, dinv, b1, B1, n);

  // ---- layer 2
  gemm_nodes<64><<<gblocks, 256, 0, stream>>>(B1, W2, dinv, B0h);
  gather_agg<<<pull_blocks, 256, 0, stream>>>(rowptr, colidx,
      (const __half2*)B0h, dinv, b2, B1, n);

  // ---- FC head
  gemm_fc<<<gblocks, 256, 0, stream>>>(B1, Wfc, bfc, out);
}

// Round 13
// 300.960 us; speedup vs baseline: 2.3383x; 1.0864x over previous
//
#include <hip/hip_runtime.h>
#include <hip/hip_fp16.h>

#define HID 64
#define SH 9          // log2(nodes per bucket)
#define BKN 512       // nodes per bucket
#define MAXB1 256     // max buckets supported (n <= 131072)
#define NBLK 512      // edge-chunk blocks for the counting sort
typedef unsigned int u32;

// ---------------------------------------------------------------- per-(block,bucket) histogram
// deterministic contiguous chunks; LDS-staged; NO global atomics
__global__ __launch_bounds__(256) void count_chunks(const int* __restrict__ dst,
                                                    int* __restrict__ cnt2,
                                                    int E, int nbk) {
  __shared__ int lc[MAXB1];
  const int t = threadIdx.x;
  for (int b = t; b < nbk; b += 256) lc[b] = 0;
  __syncthreads();
  const int C = (E + NBLK - 1) / NBLK;
  const int s0 = blockIdx.x * C;
  const int s1 = min(s0 + C, E);
  for (int i = s0 + t; i < s1; i += 256) atomicAdd(&lc[dst[i] >> SH], 1);
  __syncthreads();
  for (int b = t; b < nbk; b += 256)
    cnt2[(size_t)b * NBLK + blockIdx.x] = lc[b];  // bucket-major for the scan
}

// ---------------------------------------------------------------- generic hierarchical scan
__global__ __launch_bounds__(256) void scan_blocks(const int* __restrict__ v_in,
                                                   int* __restrict__ excl,
                                                   int* __restrict__ bsum, int n) {
  __shared__ int s[256];
  const int t = threadIdx.x;
  const int i = blockIdx.x * 256 + t;
  const int v = (i < n) ? v_in[i] : 0;
  s[t] = v;
  __syncthreads();
  for (int off = 1; off < 256; off <<= 1) {
    const int u = (t >= off) ? s[t - off] : 0;
    __syncthreads();
    s[t] += u;
    __syncthreads();
  }
  if (i < n) excl[i] = s[t] - v;
  if (t == 255) bsum[blockIdx.x] = s[255];
}

__global__ __launch_bounds__(512) void scan_top(int* bsum, int nb) {
  __shared__ int s[512];
  const int t = threadIdx.x;
  const int v = (t < nb) ? bsum[t] : 0;
  s[t] = v;
  __syncthreads();
  for (int off = 1; off < 512; off <<= 1) {
    const int u = (t >= off) ? s[t - off] : 0;
    __syncthreads();
    s[t] += u;
    __syncthreads();
  }
  if (t < nb) bsum[t] = s[t] - v;
}

// add block offsets to the cnt2-scan and extract per-bucket bases
__global__ __launch_bounds__(256) void add_offsets2(int* __restrict__ off,
                                                    const int* __restrict__ bsum,
                                                    int* __restrict__ boff,
                                                    int NE, int E, int nbk) {
  const int m = blockIdx.x * 256 + threadIdx.x;
  if (m < NE) {
    const int v = off[m] + bsum[blockIdx.x];
    off[m] = v;
    if ((m & (NBLK - 1)) == 0) boff[m >> 9] = v;  // NBLK = 512
  }
  if (m == 0) boff[nbk] = E;
}

// plain add_offsets for the rowptr scan
__global__ __launch_bounds__(256) void add_offsets(int* __restrict__ rowptr,
                                                   const int* __restrict__ bsum,
                                                   int n, int E) {
  const int i = blockIdx.x * 256 + threadIdx.x;
  if (i < n) rowptr[i] += bsum[blockIdx.x];
  if (i == 0) rowptr[n] = E;
}

// ---------------------------------------------------------------- fill pairs, deterministic
// packed u32: (dstLocal<<17) | src. Each (block,bucket) segment is block-private
// and contiguous; boundary 64B lines shared by at most 2 adjacent blocks.
__global__ __launch_bounds__(256) void fill_pairs(const int* __restrict__ src,
                                                  const int* __restrict__ dst,
                                                  const int* __restrict__ off,
                                                  u32* __restrict__ pairs,
                                                  int E, int nbk) {
  __shared__ int lbase[MAXB1];
  __shared__ int lrank[MAXB1];
  const int t = threadIdx.x;
  for (int b = t; b < nbk; b += 256) {
    lbase[b] = off[(size_t)b * NBLK + blockIdx.x];
    lrank[b] = 0;
  }
  __syncthreads();
  const int C = (E + NBLK - 1) / NBLK;
  const int s0 = blockIdx.x * C;
  const int s1 = min(s0 + C, E);
  for (int i = s0 + t; i < s1; i += 256) {
    const int d = dst[i];
    const int b = d >> SH;
    const int r = atomicAdd(&lrank[b], 1);
    pairs[lbase[b] + r] = ((u32)(d & (BKN - 1)) << 17) | (u32)src[i];
  }
}

// ---------------------------------------------------------------- per-node degree + dinv
__global__ __launch_bounds__(256) void bucket_deg(const u32* __restrict__ pairs,
                                                  const int* __restrict__ boff,
                                                  int* __restrict__ deg,
                                                  float* __restrict__ dinv, int n) {
  __shared__ int ldeg[BKN];
  const int bkt = blockIdx.x;
  const int t = threadIdx.x;
  for (int i = t; i < BKN; i += 256) ldeg[i] = 0;
  __syncthreads();
  const int beg = boff[bkt], end = boff[bkt + 1];
  for (int e = beg + t; e < end; e += 256) atomicAdd(&ldeg[pairs[e] >> 17], 1);
  __syncthreads();
  const int base = bkt * BKN;
  for (int i = t; i < BKN; i += 256) {
    const int node = base + i;
    if (node < n) {
      const int dg = ldeg[i];
      deg[node] = dg;
      dinv[node] = rsqrtf((float)(dg + 1));  // +1 self-loop
    }
  }
}

// ---------------------------------------------------------------- exact CSR fill
__global__ __launch_bounds__(256) void local_fill2(const u32* __restrict__ pairs,
                                                   const int* __restrict__ boff,
                                                   const int* __restrict__ rowptr,
                                                   int* __restrict__ colidx, int n) {
  __shared__ int lcur[BKN / 2];
  const int bkt = blockIdx.x >> 1;
  const int half = blockIdx.x & 1;
  const int nb0 = bkt * BKN + half * (BKN / 2);
  const int t = threadIdx.x;
  if (t < BKN / 2) {
    const int node = nb0 + t;
    lcur[t] = (node < n) ? rowptr[node] : 0;
  }
  __syncthreads();
  const int beg = boff[bkt], end = boff[bkt + 1];
  for (int e = beg + t; e < end; e += 256) {
    const u32 p = pairs[e];
    const int dloc = (int)(p >> 17);
    if ((dloc >> 8) == half) {
      const int pos = atomicAdd(&lcur[dloc & 255], 1);
      colidx[pos] = (int)(p & 0x1FFFF);
    }
  }
}

// ---------------------------------------------------------------- dense transform
// g[i, c] = fp16( dinv[i] * sum_k x[i,k] * W[k,c] )
// thread = (row, 4-col group): per 4 k-steps, 1 broadcast xl float4 + 4 Wl
// float4 rows feed 16 fmafs (0.31 LDS instr/fmaf, conflict-free).
template <int K>
__global__ __launch_bounds__(256) void gemm_nodes(const float* __restrict__ x,
                                                  const float* __restrict__ W,
                                                  const float* __restrict__ dinv,
                                                  __half* __restrict__ out) {
  __shared__ float Wl[K * 64];
  __shared__ float xl[16][K + 4];  // +4 pad: r-groups land on distinct banks
  const int tid = threadIdx.x;
  for (int i = tid; i < K * 16; i += 256)
    reinterpret_cast<float4*>(Wl)[i] = reinterpret_cast<const float4*>(W)[i];
  const int row0 = blockIdx.x * 16;
  for (int i = tid; i < 16 * (K / 4); i += 256) {
    const int r = i / (K / 4), q = i % (K / 4);
    reinterpret_cast<float4*>(&xl[r][0])[q] =
        reinterpret_cast<const float4*>(x + (size_t)(row0 + r) * K)[q];
  }
  __syncthreads();
  const int r = tid >> 4;           // row 0..15
  const int cg = (tid & 15) << 2;   // col group base 0,4,...,60
  float4 acc = {0.f, 0.f, 0.f, 0.f};
#pragma unroll
  for (int k = 0; k < K; k += 4) {
    const float4 xv = *reinterpret_cast<const float4*>(&xl[r][k]);      // broadcast
    const float4 w0 = *reinterpret_cast<const float4*>(&Wl[(k + 0) * 64 + cg]);
    const float4 w1 = *reinterpret_cast<const float4*>(&Wl[(k + 1) * 64 + cg]);
    const float4 w2 = *reinterpret_cast<const float4*>(&Wl[(k + 2) * 64 + cg]);
    const float4 w3 = *reinterpret_cast<const float4*>(&Wl[(k + 3) * 64 + cg]);
    acc.x = fmaf(xv.w, w3.x, fmaf(xv.z, w2.x, fmaf(xv.y, w1.x, fmaf(xv.x, w0.x, acc.x))));
    acc.y = fmaf(xv.w, w3.y, fmaf(xv.z, w2.y, fmaf(xv.y, w1.y, fmaf(xv.x, w0.y, acc.y))));
    acc.z = fmaf(xv.w, w3.z, fmaf(xv.z, w2.z, fmaf(xv.y, w1.z, fmaf(xv.x, w0.z, acc.z))));
    acc.w = fmaf(xv.w, w3.w, fmaf(xv.z, w2.w, fmaf(xv.y, w1.w, fmaf(xv.x, w0.w, acc.w))));
  }
  const int grow = row0 + r;
  const float di = dinv[grow];
  const __half2 h01 = __floats2half2_rn(acc.x * di, acc.y * di);
  const __half2 h23 = __floats2half2_rn(acc.z * di, acc.w * di);
  __half2* op = reinterpret_cast<__half2*>(out + (size_t)grow * 64 + cg);
  op[0] = h01;
  op[1] = h23;
}

// ---------------------------------------------------------------- pull aggregation
// one wave per node, 2 edges per load instr (half2 rows), 16 loads in flight
// per half-wave = 32 edges per wave-iter.
__global__ __launch_bounds__(256) void gather_agg(const int* __restrict__ rowptr,
                                                  const int* __restrict__ colidx,
                                                  const __half2* __restrict__ g2,
                                                  const float* __restrict__ dinv,
                                                  const float* __restrict__ bias,
                                                  float* __restrict__ out, int n) {
  const int lane = threadIdx.x & 63;
  const int node = (blockIdx.x * 256 + threadIdx.x) >> 6;
  if (node >= n) return;
  const int h = lane >> 5;   // which edge of each pair this half-wave owns
  const int l = lane & 31;   // feature-pair index
  const int beg = rowptr[node];
  const int end = rowptr[node + 1];
  float2 acc = {0.f, 0.f};
  int e = beg + h;
  for (; e + 30 < end; e += 32) {  // 32 edges/wave-iter, 16 loads in flight/half
    int s[16];
#pragma unroll
    for (int j = 0; j < 16; ++j) s[j] = colidx[e + 2 * j];
    float2 v[16];
#pragma unroll
    for (int j = 0; j < 16; ++j)
      v[j] = __half22float2(g2[((u32)s[j] << 5) + (u32)l]);
#pragma unroll
    for (int j = 0; j < 16; ++j) {
      acc.x += v[j].x;
      acc.y += v[j].y;
    }
  }
  for (; e + 6 < end; e += 8) {  // 8 edges/wave-iter
    const int s0 = colidx[e + 0], s1 = colidx[e + 2];
    const int s2 = colidx[e + 4], s3 = colidx[e + 6];
    const float2 v0 = __half22float2(g2[((u32)s0 << 5) + (u32)l]);
    const float2 v1 = __half22float2(g2[((u32)s1 << 5) + (u32)l]);
    const float2 v2 = __half22float2(g2[((u32)s2 << 5) + (u32)l]);
    const float2 v3 = __half22float2(g2[((u32)s3 << 5) + (u32)l]);
    acc.x += (v0.x + v1.x) + (v2.x + v3.x);
    acc.y += (v0.y + v1.y) + (v2.y + v3.y);
  }
  for (; e < end; e += 2) {  // ragged tail
    const float2 v = __half22float2(g2[((u32)colidx[e] << 5) + (u32)l]);
    acc.x += v.x;
    acc.y += v.y;
  }
  // cross-half combine
  acc.x += __shfl_xor(acc.x, 32);
  acc.y += __shfl_xor(acc.y, 32);
  // self-loop
  const float2 sv = __half22float2(g2[((u32)node << 5) + (u32)l]);
  acc.x += sv.x;
  acc.y += sv.y;
  const float di = dinv[node];
  const float2 bb = reinterpret_cast<const float2*>(bias)[l];
  float2 r;
  r.x = fmaxf(fmaf(acc.x, di, bb.x), 0.f);
  r.y = fmaxf(fmaf(acc.y, di, bb.y), 0.f);
  if (h == 0) reinterpret_cast<float2*>(out)[(size_t)node * 32 + l] = r;
}

// ---------------------------------------------------------------- final FC (64 -> 11)
__global__ __launch_bounds__(256) void gemm_fc(const float* __restrict__ h,
                                               const float* __restrict__ W,
                                               const float* __restrict__ b,
                                               float* __restrict__ out) {
  __shared__ float Wl[772];
  __shared__ float xl[16][68];
  const int tid = threadIdx.x;
  for (int i = tid; i < 772; i += 256) Wl[i] = 0.f;
  __syncthreads();
  for (int i = tid; i < 64 * 11; i += 256) Wl[(i / 11) * 12 + (i % 11)] = W[i];
  const int row0 = blockIdx.x * 16;
  for (int i = tid; i < 16 * 16; i += 256) {
    const int r = i >> 4, q = i & 15;
    const float4 v = reinterpret_cast<const float4*>(h + (size_t)(row0 + r) * 64)[q];
    xl[r][q * 4 + 0] = v.x; xl[r][q * 4 + 1] = v.y;
    xl[r][q * 4 + 2] = v.z; xl[r][q * 4 + 3] = v.w;
  }
  __syncthreads();
  const int r = tid >> 4, c = tid & 15;
  float acc = 0.f;
#pragma unroll
  for (int k = 0; k < 64; k += 4) {
    acc = fmaf(xl[r][k + 0], Wl[(k + 0) * 12 + c], acc);
    acc = fmaf(xl[r][k + 1], Wl[(k + 1) * 12 + c], acc);
    acc = fmaf(xl[r][k + 2], Wl[(k + 2) * 12 + c], acc);
    acc = fmaf(xl[r][k + 3], Wl[(k + 3) * 12 + c], acc);
  }
  if (c < 11) out[(size_t)(row0 + r) * 11 + c] = acc + b[c];
}

// ---------------------------------------------------------------- launch
extern "C" void kernel_launch(void* const* d_in, const int* in_sizes, int n_in,
                              void* d_out, int out_size, void* d_ws, size_t ws_size,
                              hipStream_t stream) {
  const float* x   = (const float*)d_in[0];
  const int*   ei  = (const int*)d_in[1];   // [2, E] int32
  const float* W1  = (const float*)d_in[2];
  const float* b1  = (const float*)d_in[3];
  const float* W2  = (const float*)d_in[4];
  const float* b2  = (const float*)d_in[5];
  const float* Wfc = (const float*)d_in[6];
  const float* bfc = (const float*)d_in[7];
  float* out = (float*)d_out;

  const int n = in_sizes[0] / 128;  // 100000
  const int E = in_sizes[1] / 2;    // 3200000
  const int* src = ei;
  const int* dst = ei + E;
  const int nbk = (n + BKN - 1) >> SH;  // 196 buckets
  const int NE = nbk * NBLK;            // 100352 count entries

  char* ws = (char*)d_ws;
  size_t o = 0;
  auto alloc = [&](size_t bytes) {
    char* p = ws + o;
    o += (bytes + 255) & ~(size_t)255;
    return p;
  };
  int*    deg    = (int*)   alloc((size_t)n * 4);
  float*  dinv   = (float*) alloc((size_t)n * 4);
  int*    rowptr = (int*)   alloc((size_t)(n + 1) * 4);
  int*    bsum   = (int*)   alloc(512 * 4);
  int*    cnt2   = (int*)   alloc((size_t)NE * 4);      // [b][blk]
  int*    off    = (int*)   alloc((size_t)NE * 4);      // scanned
  int*    bsum2  = (int*)   alloc(512 * 4);
  int*    boff   = (int*)   alloc((size_t)(nbk + 1) * 4);
  u32*    pairs  = (u32*)   alloc((size_t)E * 4);
  int*    colidx = (int*)   alloc((size_t)E * 4);
  __half* B0h    = (__half*)alloc((size_t)n * HID * 2); // g fp16
  float*  B1     = (float*) alloc((size_t)n * HID * 4); // layer out
  if (o > ws_size) return;

  const int nb  = (n + 255) / 256;   // 391 rowptr-scan blocks
  const int nb2 = (NE + 255) / 256;  // 392 offset-scan blocks
  const int gblocks = n / 16;        // 6250 gemm blocks

  // ---- graph preprocessing (deterministic counting sort; no global atomics)
  count_chunks<<<NBLK, 256, 0, stream>>>(dst, cnt2, E, nbk);
  scan_blocks<<<nb2, 256, 0, stream>>>(cnt2, off, bsum2, NE);
  scan_top<<<1, 512, 0, stream>>>(bsum2, nb2);
  add_offsets2<<<nb2, 256, 0, stream>>>(off, bsum2, boff, NE, E, nbk);
  fill_pairs<<<NBLK, 256, 0, stream>>>(src, dst, off, pairs, E, nbk);
  bucket_deg<<<nbk, 256, 0, stream>>>(pairs, boff, deg, dinv, n);
  scan_blocks<<<nb, 256, 0, stream>>>(deg, rowptr, bsum, n);
  scan_top<<<1, 512, 0, stream>>>(bsum, nb);
  add_offsets<<<nb, 256, 0, stream>>>(rowptr, bsum, n, E);
  local_fill2<<<nbk * 2, 256, 0, stream>>>(pairs, boff, rowptr, colidx, n);

  const int pull_blocks = (n * 64 + 255) / 256;  // one wave per node

  // ---- layer 1
  gemm_nodes<128><<<gblocks, 256, 0, stream>>>(x, W1, dinv, B0h);
  gather_agg<<<pull_blocks, 256, 0, stream>>>(rowptr, colidx,
      (const __half2*)B0h, dinv, b1, B1, n);

  // ---- layer 2
  gemm_nodes<64><<<gblocks, 256, 0, stream>>>(B1, W2, dinv, B0h);
  gather_agg<<<pull_blocks, 256, 0, stream>>>(rowptr, colidx,
      (const __half2*)B0h, dinv, b2, B1, n);

  // ---- FC head
  gemm_fc<<<gblocks, 256, 0, stream>>>(B1, Wfc, bfc, out);
}

// Round 14
// 276.472 us; speedup vs baseline: 2.5454x; 1.0886x over previous
//
#include <hip/hip_runtime.h>
#include <hip/hip_fp16.h>

#define HID 64
#define SH 9          // log2(nodes per bucket)
#define BKN 512       // nodes per bucket
#define MAXB1 256     // max buckets supported (n <= 131072)
#define NBLK 512      // edge-chunk blocks for the counting sort
#define MAXPAIR 24576 // LDS pair-cache (96 KB); expected bucket size ~16.3K
typedef unsigned int u32;

// ---------------------------------------------------------------- per-(block,bucket) histogram
__global__ __launch_bounds__(256) void count_chunks(const int* __restrict__ dst,
                                                    int* __restrict__ cnt2,
                                                    int E, int nbk) {
  __shared__ int lc[MAXB1];
  const int t = threadIdx.x;
  for (int b = t; b < nbk; b += 256) lc[b] = 0;
  __syncthreads();
  const int C = (E + NBLK - 1) / NBLK;
  const int s0 = blockIdx.x * C;
  const int s1 = min(s0 + C, E);
  for (int i = s0 + t; i < s1; i += 256) atomicAdd(&lc[dst[i] >> SH], 1);
  __syncthreads();
  for (int b = t; b < nbk; b += 256)
    cnt2[(size_t)b * NBLK + blockIdx.x] = lc[b];  // bucket-major for the scan
}

// ---------------------------------------------------------------- hierarchical scan (cnt2)
__global__ __launch_bounds__(256) void scan_blocks(const int* __restrict__ v_in,
                                                   int* __restrict__ excl,
                                                   int* __restrict__ bsum, int n) {
  __shared__ int s[256];
  const int t = threadIdx.x;
  const int i = blockIdx.x * 256 + t;
  const int v = (i < n) ? v_in[i] : 0;
  s[t] = v;
  __syncthreads();
  for (int off = 1; off < 256; off <<= 1) {
    const int u = (t >= off) ? s[t - off] : 0;
    __syncthreads();
    s[t] += u;
    __syncthreads();
  }
  if (i < n) excl[i] = s[t] - v;
  if (t == 255) bsum[blockIdx.x] = s[255];
}

__global__ __launch_bounds__(512) void scan_top(int* bsum, int nb) {
  __shared__ int s[512];
  const int t = threadIdx.x;
  const int v = (t < nb) ? bsum[t] : 0;
  s[t] = v;
  __syncthreads();
  for (int off = 1; off < 512; off <<= 1) {
    const int u = (t >= off) ? s[t - off] : 0;
    __syncthreads();
    s[t] += u;
    __syncthreads();
  }
  if (t < nb) bsum[t] = s[t] - v;
}

__global__ __launch_bounds__(256) void add_offsets2(int* __restrict__ off,
                                                    const int* __restrict__ bsum,
                                                    int* __restrict__ boff,
                                                    int NE, int E, int nbk) {
  const int m = blockIdx.x * 256 + threadIdx.x;
  if (m < NE) {
    const int v = off[m] + bsum[blockIdx.x];
    off[m] = v;
    if ((m & (NBLK - 1)) == 0) boff[m >> 9] = v;  // NBLK = 512
  }
  if (m == 0) boff[nbk] = E;
}

// ---------------------------------------------------------------- fill pairs (deterministic)
// packed u32: (dstLocal<<17) | src
__global__ __launch_bounds__(256) void fill_pairs(const int* __restrict__ src,
                                                  const int* __restrict__ dst,
                                                  const int* __restrict__ off,
                                                  u32* __restrict__ pairs,
                                                  int E, int nbk) {
  __shared__ int lbase[MAXB1];
  __shared__ int lrank[MAXB1];
  const int t = threadIdx.x;
  for (int b = t; b < nbk; b += 256) {
    lbase[b] = off[(size_t)b * NBLK + blockIdx.x];
    lrank[b] = 0;
  }
  __syncthreads();
  const int C = (E + NBLK - 1) / NBLK;
  const int s0 = blockIdx.x * C;
  const int s1 = min(s0 + C, E);
  for (int i = s0 + t; i < s1; i += 256) {
    const int d = dst[i];
    const int b = d >> SH;
    const int r = atomicAdd(&lrank[b], 1);
    pairs[lbase[b] + r] = ((u32)(d & (BKN - 1)) << 17) | (u32)src[i];
  }
}

// ---------------------------------------------------------------- fused CSR build
// one 512-thread block per bucket: cache pairs in LDS, count -> local prefix
// (rowptr = boff[bkt] + excl), write rowptr/dinv coalesced, place colidx.
// Replaces bucket_deg + rowptr scan trio + local_fill2.
__global__ __launch_bounds__(512) void bucket_csr(const u32* __restrict__ pairs,
                                                  const int* __restrict__ boff,
                                                  int* __restrict__ rowptr,
                                                  float* __restrict__ dinv,
                                                  int* __restrict__ colidx,
                                                  int n, int nbk) {
  __shared__ u32 pc[MAXPAIR];  // 96 KB pair cache
  __shared__ int ldeg[BKN];
  __shared__ int lofs[BKN];
  const int bkt = blockIdx.x;
  const int t = threadIdx.x;
  ldeg[t] = 0;
  __syncthreads();
  const int beg = boff[bkt], end = boff[bkt + 1];
  const int cnt = end - beg;
  const bool cached = (cnt <= MAXPAIR);
  for (int e = t; e < cnt; e += 512) {
    const u32 p = pairs[beg + e];
    if (cached) pc[e] = p;
    atomicAdd(&ldeg[p >> 17], 1);
  }
  __syncthreads();
  const int v = ldeg[t];
  lofs[t] = v;
  __syncthreads();
  for (int o = 1; o < 512; o <<= 1) {  // Hillis-Steele inclusive scan
    const int u = (t >= o) ? lofs[t - o] : 0;
    __syncthreads();
    lofs[t] += u;
    __syncthreads();
  }
  const int base = beg + lofs[t] - v;  // exclusive
  const int node = bkt * BKN + t;
  if (node < n) {
    rowptr[node] = base;
    dinv[node] = rsqrtf((float)(v + 1));  // +1 self-loop
  }
  if (bkt == nbk - 1 && t == 511) rowptr[n] = end;  // == E
  __syncthreads();
  ldeg[t] = base;  // reuse as absolute cursor
  __syncthreads();
  for (int e = t; e < cnt; e += 512) {
    const u32 p = cached ? pc[e] : pairs[beg + e];
    const int pos = atomicAdd(&ldeg[p >> 17], 1);
    colidx[pos] = (int)(p & 0x1FFFF);
  }
}

// ---------------------------------------------------------------- dense transform (fp32 in)
// g[i, c] = fp16( dinv[i] * sum_k x[i,k] * W[k,c] )
template <int K>
__global__ __launch_bounds__(256) void gemm_nodes(const float* __restrict__ x,
                                                  const float* __restrict__ W,
                                                  const float* __restrict__ dinv,
                                                  __half* __restrict__ out) {
  __shared__ float Wl[K * 64];
  __shared__ float xl[16][K + 4];
  const int tid = threadIdx.x;
  for (int i = tid; i < K * 16; i += 256)
    reinterpret_cast<float4*>(Wl)[i] = reinterpret_cast<const float4*>(W)[i];
  const int row0 = blockIdx.x * 16;
  for (int i = tid; i < 16 * (K / 4); i += 256) {
    const int r = i / (K / 4), q = i % (K / 4);
    reinterpret_cast<float4*>(&xl[r][0])[q] =
        reinterpret_cast<const float4*>(x + (size_t)(row0 + r) * K)[q];
  }
  __syncthreads();
  const int r = tid >> 4;
  const int cg = (tid & 15) << 2;
  float4 acc = {0.f, 0.f, 0.f, 0.f};
#pragma unroll
  for (int k = 0; k < K; k += 4) {
    const float4 xv = *reinterpret_cast<const float4*>(&xl[r][k]);
    const float4 w0 = *reinterpret_cast<const float4*>(&Wl[(k + 0) * 64 + cg]);
    const float4 w1 = *reinterpret_cast<const float4*>(&Wl[(k + 1) * 64 + cg]);
    const float4 w2 = *reinterpret_cast<const float4*>(&Wl[(k + 2) * 64 + cg]);
    const float4 w3 = *reinterpret_cast<const float4*>(&Wl[(k + 3) * 64 + cg]);
    acc.x = fmaf(xv.w, w3.x, fmaf(xv.z, w2.x, fmaf(xv.y, w1.x, fmaf(xv.x, w0.x, acc.x))));
    acc.y = fmaf(xv.w, w3.y, fmaf(xv.z, w2.y, fmaf(xv.y, w1.y, fmaf(xv.x, w0.y, acc.y))));
    acc.z = fmaf(xv.w, w3.z, fmaf(xv.z, w2.z, fmaf(xv.y, w1.z, fmaf(xv.x, w0.z, acc.z))));
    acc.w = fmaf(xv.w, w3.w, fmaf(xv.z, w2.w, fmaf(xv.y, w1.w, fmaf(xv.x, w0.w, acc.w))));
  }
  const int grow = row0 + r;
  const float di = dinv[grow];
  __half2* op = reinterpret_cast<__half2*>(out + (size_t)grow * 64 + cg);
  op[0] = __floats2half2_rn(acc.x * di, acc.y * di);
  op[1] = __floats2half2_rn(acc.z * di, acc.w * di);
}

// ---------------------------------------------------------------- dense transform (fp16 in, K=64)
__global__ __launch_bounds__(256) void gemm_nodes_h(const __half* __restrict__ x,
                                                    const float* __restrict__ W,
                                                    const float* __restrict__ dinv,
                                                    __half* __restrict__ out) {
  __shared__ float Wl[64 * 64];
  __shared__ float xl[16][68];
  const int tid = threadIdx.x;
  for (int i = tid; i < 64 * 16; i += 256)
    reinterpret_cast<float4*>(Wl)[i] = reinterpret_cast<const float4*>(W)[i];
  const int row0 = blockIdx.x * 16;
  if (tid < 128) {  // 16 rows x 8 chunks of 8 fp16 (16B loads)
    const int r = tid >> 3, q = tid & 7;
    const float4 hv = *reinterpret_cast<const float4*>(
        x + (size_t)(row0 + r) * 64 + q * 8);
    const __half2* hp = reinterpret_cast<const __half2*>(&hv);
#pragma unroll
    for (int j = 0; j < 4; ++j) {
      const float2 f = __half22float2(hp[j]);
      xl[r][q * 8 + 2 * j + 0] = f.x;
      xl[r][q * 8 + 2 * j + 1] = f.y;
    }
  }
  __syncthreads();
  const int r = tid >> 4;
  const int cg = (tid & 15) << 2;
  float4 acc = {0.f, 0.f, 0.f, 0.f};
#pragma unroll
  for (int k = 0; k < 64; k += 4) {
    const float4 xv = *reinterpret_cast<const float4*>(&xl[r][k]);
    const float4 w0 = *reinterpret_cast<const float4*>(&Wl[(k + 0) * 64 + cg]);
    const float4 w1 = *reinterpret_cast<const float4*>(&Wl[(k + 1) * 64 + cg]);
    const float4 w2 = *reinterpret_cast<const float4*>(&Wl[(k + 2) * 64 + cg]);
    const float4 w3 = *reinterpret_cast<const float4*>(&Wl[(k + 3) * 64 + cg]);
    acc.x = fmaf(xv.w, w3.x, fmaf(xv.z, w2.x, fmaf(xv.y, w1.x, fmaf(xv.x, w0.x, acc.x))));
    acc.y = fmaf(xv.w, w3.y, fmaf(xv.z, w2.y, fmaf(xv.y, w1.y, fmaf(xv.x, w0.y, acc.y))));
    acc.z = fmaf(xv.w, w3.z, fmaf(xv.z, w2.z, fmaf(xv.y, w1.z, fmaf(xv.x, w0.z, acc.z))));
    acc.w = fmaf(xv.w, w3.w, fmaf(xv.z, w2.w, fmaf(xv.y, w1.w, fmaf(xv.x, w0.w, acc.w))));
  }
  const int grow = row0 + r;
  const float di = dinv[grow];
  __half2* op = reinterpret_cast<__half2*>(out + (size_t)grow * 64 + cg);
  op[0] = __floats2half2_rn(acc.x * di, acc.y * di);
  op[1] = __floats2half2_rn(acc.z * di, acc.w * di);
}

// ---------------------------------------------------------------- pull aggregation
// one wave per node, 2 edges per load (half2 rows), 16 loads in flight per half
template <bool FP16OUT>
__global__ __launch_bounds__(256) void gather_agg(const int* __restrict__ rowptr,
                                                  const int* __restrict__ colidx,
                                                  const __half2* __restrict__ g2,
                                                  const float* __restrict__ dinv,
                                                  const float* __restrict__ bias,
                                                  void* __restrict__ outp, int n) {
  const int lane = threadIdx.x & 63;
  const int node = (blockIdx.x * 256 + threadIdx.x) >> 6;
  if (node >= n) return;
  const int h = lane >> 5;
  const int l = lane & 31;
  const int beg = rowptr[node];
  const int end = rowptr[node + 1];
  float2 acc = {0.f, 0.f};
  int e = beg + h;
  for (; e + 30 < end; e += 32) {  // 32 edges/wave-iter
    int s[16];
#pragma unroll
    for (int j = 0; j < 16; ++j) s[j] = colidx[e + 2 * j];
    float2 v[16];
#pragma unroll
    for (int j = 0; j < 16; ++j)
      v[j] = __half22float2(g2[((u32)s[j] << 5) + (u32)l]);
#pragma unroll
    for (int j = 0; j < 16; ++j) {
      acc.x += v[j].x;
      acc.y += v[j].y;
    }
  }
  for (; e + 6 < end; e += 8) {
    const int s0 = colidx[e + 0], s1 = colidx[e + 2];
    const int s2 = colidx[e + 4], s3 = colidx[e + 6];
    const float2 v0 = __half22float2(g2[((u32)s0 << 5) + (u32)l]);
    const float2 v1 = __half22float2(g2[((u32)s1 << 5) + (u32)l]);
    const float2 v2 = __half22float2(g2[((u32)s2 << 5) + (u32)l]);
    const float2 v3 = __half22float2(g2[((u32)s3 << 5) + (u32)l]);
    acc.x += (v0.x + v1.x) + (v2.x + v3.x);
    acc.y += (v0.y + v1.y) + (v2.y + v3.y);
  }
  for (; e < end; e += 2) {
    const float2 v = __half22float2(g2[((u32)colidx[e] << 5) + (u32)l]);
    acc.x += v.x;
    acc.y += v.y;
  }
  acc.x += __shfl_xor(acc.x, 32);
  acc.y += __shfl_xor(acc.y, 32);
  const float2 sv = __half22float2(g2[((u32)node << 5) + (u32)l]);  // self-loop
  acc.x += sv.x;
  acc.y += sv.y;
  const float di = dinv[node];
  const float2 bb = reinterpret_cast<const float2*>(bias)[l];
  float2 r;
  r.x = fmaxf(fmaf(acc.x, di, bb.x), 0.f);
  r.y = fmaxf(fmaf(acc.y, di, bb.y), 0.f);
  if (h == 0) {
    if (FP16OUT)
      reinterpret_cast<__half2*>(outp)[(size_t)node * 32 + l] =
          __floats2half2_rn(r.x, r.y);
    else
      reinterpret_cast<float2*>(outp)[(size_t)node * 32 + l] = r;
  }
}

// ---------------------------------------------------------------- final FC (64 -> 11)
__global__ __launch_bounds__(256) void gemm_fc(const float* __restrict__ h,
                                               const float* __restrict__ W,
                                               const float* __restrict__ b,
                                               float* __restrict__ out) {
  __shared__ float Wl[772];
  __shared__ float xl[16][68];
  const int tid = threadIdx.x;
  for (int i = tid; i < 772; i += 256) Wl[i] = 0.f;
  __syncthreads();
  for (int i = tid; i < 64 * 11; i += 256) Wl[(i / 11) * 12 + (i % 11)] = W[i];
  const int row0 = blockIdx.x * 16;
  for (int i = tid; i < 16 * 16; i += 256) {
    const int r = i >> 4, q = i & 15;
    const float4 v = reinterpret_cast<const float4*>(h + (size_t)(row0 + r) * 64)[q];
    xl[r][q * 4 + 0] = v.x; xl[r][q * 4 + 1] = v.y;
    xl[r][q * 4 + 2] = v.z; xl[r][q * 4 + 3] = v.w;
  }
  __syncthreads();
  const int r = tid >> 4, c = tid & 15;
  float acc = 0.f;
#pragma unroll
  for (int k = 0; k < 64; k += 4) {
    acc = fmaf(xl[r][k + 0], Wl[(k + 0) * 12 + c], acc);
    acc = fmaf(xl[r][k + 1], Wl[(k + 1) * 12 + c], acc);
    acc = fmaf(xl[r][k + 2], Wl[(k + 2) * 12 + c], acc);
    acc = fmaf(xl[r][k + 3], Wl[(k + 3) * 12 + c], acc);
  }
  if (c < 11) out[(size_t)(row0 + r) * 11 + c] = acc + b[c];
}

// ---------------------------------------------------------------- launch
extern "C" void kernel_launch(void* const* d_in, const int* in_sizes, int n_in,
                              void* d_out, int out_size, void* d_ws, size_t ws_size,
                              hipStream_t stream) {
  const float* x   = (const float*)d_in[0];
  const int*   ei  = (const int*)d_in[1];   // [2, E] int32
  const float* W1  = (const float*)d_in[2];
  const float* b1  = (const float*)d_in[3];
  const float* W2  = (const float*)d_in[4];
  const float* b2  = (const float*)d_in[5];
  const float* Wfc = (const float*)d_in[6];
  const float* bfc = (const float*)d_in[7];
  float* out = (float*)d_out;

  const int n = in_sizes[0] / 128;  // 100000
  const int E = in_sizes[1] / 2;    // 3200000
  const int* src = ei;
  const int* dst = ei + E;
  const int nbk = (n + BKN - 1) >> SH;  // 196 buckets
  const int NE = nbk * NBLK;            // 100352 count entries

  char* ws = (char*)d_ws;
  size_t o = 0;
  auto alloc = [&](size_t bytes) {
    char* p = ws + o;
    o += (bytes + 255) & ~(size_t)255;
    return p;
  };
  float*  dinv   = (float*) alloc((size_t)n * 4);
  int*    rowptr = (int*)   alloc((size_t)(n + 1) * 4);
  int*    cnt2   = (int*)   alloc((size_t)NE * 4);
  int*    off    = (int*)   alloc((size_t)NE * 4);
  int*    bsum2  = (int*)   alloc(512 * 4);
  int*    boff   = (int*)   alloc((size_t)(nbk + 1) * 4);
  u32*    pairs  = (u32*)   alloc((size_t)E * 4);
  int*    colidx = (int*)   alloc((size_t)E * 4);
  __half* B0h    = (__half*)alloc((size_t)n * HID * 2);  // g fp16
  __half* B1h    = (__half*)alloc((size_t)n * HID * 2);  // h1 fp16
  float*  B1f    = (float*) alloc((size_t)n * HID * 4);  // h2 fp32
  if (o > ws_size) return;

  const int nb2 = (NE + 255) / 256;  // offset-scan blocks
  const int gblocks = n / 16;        // 6250 gemm blocks

  // ---- graph preprocessing (deterministic counting sort; no global atomics)
  count_chunks<<<NBLK, 256, 0, stream>>>(dst, cnt2, E, nbk);
  scan_blocks<<<nb2, 256, 0, stream>>>(cnt2, off, bsum2, NE);
  scan_top<<<1, 512, 0, stream>>>(bsum2, nb2);
  add_offsets2<<<nb2, 256, 0, stream>>>(off, bsum2, boff, NE, E, nbk);
  fill_pairs<<<NBLK, 256, 0, stream>>>(src, dst, off, pairs, E, nbk);
  bucket_csr<<<nbk, 512, 0, stream>>>(pairs, boff, rowptr, dinv, colidx, n, nbk);

  const int pull_blocks = (n * 64 + 255) / 256;  // one wave per node

  // ---- layer 1
  gemm_nodes<128><<<gblocks, 256, 0, stream>>>(x, W1, dinv, B0h);
  gather_agg<true><<<pull_blocks, 256, 0, stream>>>(rowptr, colidx,
      (const __half2*)B0h, dinv, b1, B1h, n);

  // ---- layer 2
  gemm_nodes_h<<<gblocks, 256, 0, stream>>>(B1h, W2, dinv, B0h);
  gather_agg<false><<<pull_blocks, 256, 0, stream>>>(rowptr, colidx,
      (const __half2*)B0h, dinv, b2, B1f, n);

  // ---- FC head
  gemm_fc<<<gblocks, 256, 0, stream>>>(B1f, Wfc, bfc, out);
}